// Round 2
// baseline (324.209 us; speedup 1.0000x reference)
//
#include <hip/hip_runtime.h>
#include <hip/hip_bf16.h>

#define N_NODES 50000
#define N_EDGES 800000
#define DIM 128
#define NTILES (N_EDGES / 64)   // 12500 exactly
#define SCAN_B 196              // ceil(50000/256)
#define HIST_B 3125             // 800000/256
#define NODE_B 782              // ceil(50000/64)
#define OUTZ_B 512
#define SCAT_B 2048             // 8 sets x 256 blocks; set = bid&7 -> XCD heuristic

typedef __bf16 bf16x8 __attribute__((ext_vector_type(8)));
typedef float f32x4 __attribute__((ext_vector_type(4)));
typedef unsigned int u32x4 __attribute__((ext_vector_type(4)));
typedef short s16x2 __attribute__((ext_vector_type(2)));

__device__ __forceinline__ unsigned short f2bf(float f) {
    unsigned u = __float_as_uint(f);
    u += 0x7fffu + ((u >> 16) & 1u);          // round-to-nearest-even
    return (unsigned short)(u >> 16);
}
__device__ __forceinline__ float bf2f(unsigned short s) {
    return __uint_as_float(((unsigned)s) << 16);
}
__device__ __forceinline__ unsigned short f2bf_hw(float f) {
    __hip_bfloat16 h = __float2bfloat16(f);
    unsigned short s;
    __builtin_memcpy(&s, &h, 2);
    return s;
}
// packed bf16x2 add (v_pk_add_bf16 on gfx950) + relu via packed int16 max
// (bf16 bits: negative => sign bit => int16<0, positive ordering == float ordering)
__device__ __forceinline__ unsigned bf2_add_relu(unsigned a, unsigned b) {
    __hip_bfloat162 A, B;
    __builtin_memcpy(&A, &a, 4);
    __builtin_memcpy(&B, &b, 4);
    __hip_bfloat162 S = __hadd2(A, B);
    unsigned s;
    __builtin_memcpy(&s, &S, 4);
    s16x2 sv = __builtin_bit_cast(s16x2, s);
    s16x2 z = (s16x2){0, 0};
    return __builtin_bit_cast(unsigned, __builtin_elementwise_max(sv, z));
}

// ---- K1 (R12-proven): convert weights (blocks 0..255) + dst hist (256..3380) + zero out
// identity: [h_i, h_j-h_i] @ W2 = h_i @ (W2a - W2b) + h_j @ W2b
__global__ void prep_kernel(const float* __restrict__ W1, const float* __restrict__ W2,
                            const float* __restrict__ W3, const int* __restrict__ eidx,
                            unsigned short* __restrict__ W1t, unsigned short* __restrict__ Wat,
                            unsigned short* __restrict__ Wbt, unsigned short* __restrict__ W3t,
                            int* __restrict__ cnt, u32x4* __restrict__ outz) {
    int bid = blockIdx.x, tid = threadIdx.x;
    if (bid < 256) {
        int i = bid * 256 + tid;
        int j = i & (DIM * DIM - 1);
        int k = j >> 7, n = j & 127;
        int sec = i >> 14;
        if (sec == 0)      W1t[n * 128 + k] = f2bf(W1[k * 128 + n]);
        else if (sec == 1) Wat[n * 128 + k] = f2bf(W2[k * 128 + n] - W2[(k + 128) * 128 + n]);
        else if (sec == 2) Wbt[n * 128 + k] = f2bf(W2[(k + 128) * 128 + n]);
        else               W3t[n * 128 + k] = f2bf(W3[k * 128 + n]);
    } else if (bid < 256 + HIST_B) {
        int e = (bid - 256) * 256 + tid;      // exactly covers 800000
        atomicAdd(&cnt[eidx[N_EDGES + e]], 1);
    } else {
        int b = bid - 256 - HIST_B;
        u32x4 z = (u32x4){0u, 0u, 0u, 0u};
        for (int i = b * 256 + tid; i < N_NODES * DIM / 4; i += OUTZ_B * 256) outz[i] = z;
    }
}

// ---- K2 (R12-proven): scanA (blocks 0..195) + node GEMMs (blocks 196..977)
// node: h = bf16(x@W1+b1) -> LDS -> gA = bf16(h@Wa + b2), gB = bf16(h@Wb)
__global__ __launch_bounds__(256, 2) void scan_node_kernel(
        int* __restrict__ cnt, int* __restrict__ aux,
        const float* __restrict__ x, const unsigned short* __restrict__ W1t,
        const unsigned short* __restrict__ Wat, const unsigned short* __restrict__ Wbt,
        const float* __restrict__ b1, const float* __restrict__ b2,
        unsigned short* __restrict__ gA, unsigned short* __restrict__ gB) {
    __shared__ __align__(16) unsigned short w1t[128 * 136];   // head doubles as scan buf
    __shared__ __align__(16) unsigned short h_lds[64 * 136];
    int tid = threadIdx.x, bid = blockIdx.x;
    if (bid < SCAN_B) {
        int* buf = (int*)w1t;
        int i = bid * 256 + tid;
        int v = (i < N_NODES) ? cnt[i] : 0;
        buf[tid] = v;
        __syncthreads();
        for (int off = 1; off < 256; off <<= 1) {
            int u = (tid >= off) ? buf[tid - off] : 0;
            __syncthreads();
            buf[tid] += u;
            __syncthreads();
        }
        if (i < N_NODES) cnt[i] = buf[tid] - v;
        if (tid == 255) aux[bid] = buf[255];
        return;
    }
    int bl = bid - SCAN_B;
    #pragma unroll
    for (int it = 0; it < 8; it++) {
        int idx = (tid + it * 256) * 8;
        int n = idx >> 7, k = idx & 127;
        *(u32x4*)(&w1t[n * 136 + k]) = *(const u32x4*)(&W1t[idx]);
    }
    int w = tid >> 6, lane = tid & 63;
    int lr = lane & 15, q = lane >> 4;
    bf16x8 baf[2][4], bbf[2][4];
    float b2v[2];
    #pragma unroll
    for (int ct = 0; ct < 2; ct++) {
        int n = (2 * w + ct) * 16 + lr;
        #pragma unroll
        for (int kt = 0; kt < 4; kt++) {
            baf[ct][kt] = __builtin_bit_cast(bf16x8, *(const u32x4*)(&Wat[n * 128 + kt * 32 + q * 8]));
            bbf[ct][kt] = __builtin_bit_cast(bf16x8, *(const u32x4*)(&Wbt[n * 128 + kt * 32 + q * 8]));
        }
        b2v[ct] = b2[n];
    }
    __syncthreads();
    int row0 = bl * 64;
    int rowA = row0 + w * 16 + lr; if (rowA >= N_NODES) rowA = N_NODES - 1;
    {
        f32x4 acc[8];
        #pragma unroll
        for (int ct = 0; ct < 8; ct++) acc[ct] = (f32x4){0.f, 0.f, 0.f, 0.f};
        #pragma unroll
        for (int kt = 0; kt < 4; kt++) {
            const float* ap = x + (size_t)rowA * DIM + kt * 32 + q * 8;
            f32x4 x0 = *(const f32x4*)(ap);
            f32x4 x1 = *(const f32x4*)(ap + 4);
            bf16x8 a;
            #pragma unroll
            for (int j = 0; j < 4; j++) { a[j] = (__bf16)x0[j]; a[j + 4] = (__bf16)x1[j]; }
            #pragma unroll
            for (int ct = 0; ct < 8; ct++) {
                bf16x8 b = __builtin_bit_cast(bf16x8,
                    *(const u32x4*)(&w1t[(ct * 16 + lr) * 136 + kt * 32 + q * 8]));
                acc[ct] = __builtin_amdgcn_mfma_f32_16x16x32_bf16(a, b, acc[ct], 0, 0, 0);
            }
        }
        #pragma unroll
        for (int ct = 0; ct < 8; ct++) {
            int col = ct * 16 + lr;
            float bias = b1[col];
            #pragma unroll
            for (int r = 0; r < 4; r++)   // C/D: col=lane&15, row=quad*4+reg
                h_lds[(w * 16 + q * 4 + r) * 136 + col] = f2bf(acc[ct][r] + bias);
        }
    }
    __syncthreads();
    {
        f32x4 accA[4][2], accB[4][2];
        #pragma unroll
        for (int rt = 0; rt < 4; rt++)
            #pragma unroll
            for (int ct = 0; ct < 2; ct++) {
                accA[rt][ct] = (f32x4){0.f, 0.f, 0.f, 0.f};
                accB[rt][ct] = (f32x4){0.f, 0.f, 0.f, 0.f};
            }
        #pragma unroll
        for (int kt = 0; kt < 4; kt++) {
            #pragma unroll
            for (int rt = 0; rt < 4; rt++) {
                bf16x8 a = __builtin_bit_cast(bf16x8,
                    *(const u32x4*)(&h_lds[(rt * 16 + lr) * 136 + kt * 32 + q * 8]));
                accA[rt][0] = __builtin_amdgcn_mfma_f32_16x16x32_bf16(a, baf[0][kt], accA[rt][0], 0, 0, 0);
                accA[rt][1] = __builtin_amdgcn_mfma_f32_16x16x32_bf16(a, baf[1][kt], accA[rt][1], 0, 0, 0);
                accB[rt][0] = __builtin_amdgcn_mfma_f32_16x16x32_bf16(a, bbf[0][kt], accB[rt][0], 0, 0, 0);
                accB[rt][1] = __builtin_amdgcn_mfma_f32_16x16x32_bf16(a, bbf[1][kt], accB[rt][1], 0, 0, 0);
            }
        }
        #pragma unroll
        for (int rt = 0; rt < 4; rt++) {
            #pragma unroll
            for (int ct = 0; ct < 2; ct++) {
                int col = (2 * w + ct) * 16 + lr;
                #pragma unroll
                for (int r = 0; r < 4; r++) {
                    int row = row0 + rt * 16 + q * 4 + r;
                    if (row < N_NODES) {
                        gA[(size_t)row * DIM + col] = f2bf(accA[rt][ct][r] + b2v[ct]);
                        gB[(size_t)row * DIM + col] = f2bf(accB[rt][ct][r]);
                    }
                }
            }
        }
    }
}

// ---- K3 (R12-proven): XCD-binned scatter
__global__ __launch_bounds__(256) void scatter_kernel(
        const int* __restrict__ eidx, int* __restrict__ cursor, const int* __restrict__ aux,
        int2* __restrict__ spair) {
    __shared__ int buf[256];
    int tid = threadIdx.x, bid = blockIdx.x;
    int v = (tid < SCAN_B) ? aux[tid] : 0;
    buf[tid] = v;
    __syncthreads();
    for (int off = 1; off < 256; off <<= 1) {
        int u = (tid >= off) ? buf[tid - off] : 0;
        __syncthreads();
        buf[tid] += u;
        __syncthreads();
    }
    int excl = buf[tid] - v;
    __syncthreads();
    buf[tid] = excl;
    __syncthreads();
    int set = bid & 7;
    int j = bid >> 3;
    for (int e = j * 256 + tid; e < N_EDGES; e += (SCAT_B / 8) * 256) {
        int d = eidx[N_EDGES + e];
        if (((d >> 8) & 7) == set) {
            int s = eidx[e];
            int p = atomicAdd(&cursor[d], 1) + buf[d >> 8];
            spair[p] = make_int2(s, d);
        }
    }
}

// ---- K4: edge = relu(gA[dst]+gB[src]) -> GEMM2 -> segmented scatter-max.
// R13 change: single shared m_lds buffer (m1 and m2 are not live simultaneously)
// halves LDS 35328->17664 B; __launch_bounds__(256,8) -> 8 blocks/CU (was 4).
// Costs 2 extra barriers/iter; cross-block overlap at 2x occupancy replaces the
// old intra-block waves-2-3-run-ahead overlap. Interior segments (unique writer
// under dst-sort) use a plain coalesced 8B store instead of 2 atomicMax.
__global__ __launch_bounds__(256, 8) void edge_kernel(
        const unsigned short* __restrict__ gA,
        const unsigned short* __restrict__ gB,
        const int2* __restrict__ spair,
        const unsigned short* __restrict__ W3t,
        const float* __restrict__ b3,
        unsigned int* __restrict__ out) {
    __shared__ __align__(16) unsigned short m_lds[64 * 136];
    __shared__ int s_dst[64];

    int tid = threadIdx.x;
    int w = tid >> 6, lane = tid & 63;
    int lr = lane & 15, q = lane >> 4;
    int tr = tid >> 4;
    int c = (tid & 15) * 8;

    bf16x8 b3f[2][4];
    float b3v[2];
    #pragma unroll
    for (int ct = 0; ct < 2; ct++) {
        int n = (2 * w + ct) * 16 + lr;
        #pragma unroll
        for (int kt = 0; kt < 4; kt++)
            b3f[ct][kt] = __builtin_bit_cast(bf16x8, *(const u32x4*)(&W3t[n * 128 + kt * 32 + q * 8]));
        b3v[ct] = b3[n];
    }

    int tb = blockIdx.x;
    int2 pr[4];
    {
        int eb = tb * 64;
        #pragma unroll
        for (int it = 0; it < 4; it++) pr[it] = spair[eb + tr + 16 * it];
    }

    for (; tb < NTILES; tb += gridDim.x) {
        // m1 = relu(gA[dst]+gB[src]) — packed bf16 add + packed int relu
        #pragma unroll
        for (int it = 0; it < 4; it++) {
            int t = tr + 16 * it;
            u32x4 ga = *(const u32x4*)(&gA[(size_t)pr[it].y * DIM + c]);
            u32x4 gb = *(const u32x4*)(&gB[(size_t)pr[it].x * DIM + c]);
            u32x4 m;
            #pragma unroll
            for (int jj = 0; jj < 4; jj++)
                m[jj] = bf2_add_relu(ga[jj], gb[jj]);
            *(u32x4*)(&m_lds[t * 136 + c]) = m;
        }
        if ((tid & 15) == 0) {
            #pragma unroll
            for (int it = 0; it < 4; it++) s_dst[tr + 16 * it] = pr[it].y;
        }
        __syncthreads();   // (1) m1 + s_dst ready

        int nx = tb + (int)gridDim.x;
        int2 npr[4];
        if (nx < NTILES) {
            int eb = nx * 64;
            #pragma unroll
            for (int it = 0; it < 4; it++) npr[it] = spair[eb + tr + 16 * it];
        }

        f32x4 acc2[4][2];
        #pragma unroll
        for (int rt = 0; rt < 4; rt++)
            #pragma unroll
            for (int ct = 0; ct < 2; ct++) acc2[rt][ct] = (f32x4){0.f, 0.f, 0.f, 0.f};
        #pragma unroll
        for (int kt = 0; kt < 4; kt++) {
            #pragma unroll
            for (int rt = 0; rt < 4; rt++) {
                bf16x8 a = __builtin_bit_cast(bf16x8,
                    *(const u32x4*)(&m_lds[(rt * 16 + lr) * 136 + kt * 32 + q * 8]));
                acc2[rt][0] = __builtin_amdgcn_mfma_f32_16x16x32_bf16(a, b3f[0][kt], acc2[rt][0], 0, 0, 0);
                acc2[rt][1] = __builtin_amdgcn_mfma_f32_16x16x32_bf16(a, b3f[1][kt], acc2[rt][1], 0, 0, 0);
            }
        }
        __syncthreads();   // (2) all m1 reads done — safe to overwrite with m2

        #pragma unroll
        for (int rt = 0; rt < 4; rt++) {
            #pragma unroll
            for (int ct = 0; ct < 2; ct++) {
                int col = (2 * w + ct) * 16 + lr;
                #pragma unroll
                for (int r = 0; r < 4; r++)
                    m_lds[(rt * 16 + q * 4 + r) * 136 + col] = f2bf_hw(fmaxf(acc2[rt][ct][r] + b3v[ct], 0.f));
            }
        }
        __syncthreads();   // (3) m2 ready

        // segmax: threads 0..127 -> (col pair = tid&63, row group = tid>>6 of 32 rows)
        if (tid < 128) {
            int pair = tid & 63;
            int g = tid >> 6;                           // == wave index (0 or 1)
            const unsigned* m2p = (const unsigned*)m_lds;    // [64][68] dwords
            int r0 = g * 32;
            unsigned cur = m2p[r0 * 68 + pair];
            int d = s_dst[r0];                          // wave-uniform
            bool first = true;                          // first segment may extend before r0
            #pragma unroll 4
            for (int i = 1; i < 32; i++) {
                int dn = s_dst[r0 + i];                 // wave-uniform
                unsigned v = m2p[(r0 + i) * 68 + pair];
                if (dn != d) {                          // wave-uniform branch
                    if (first) {
                        atomicMax(&out[(size_t)d * DIM + 2 * pair],     (cur & 0xffffu) << 16);
                        atomicMax(&out[(size_t)d * DIM + 2 * pair + 1], cur & 0xffff0000u);
                    } else {
                        // interior segment: dst fully contained in this 32-row group
                        // -> unique writer -> plain coalesced store (out was zeroed)
                        uint2 st = make_uint2((cur & 0xffffu) << 16, cur & 0xffff0000u);
                        *(uint2*)(&out[(size_t)d * DIM + 2 * pair]) = st;
                    }
                    first = false;
                    d = dn; cur = v;
                } else {
                    s16x2 a2 = __builtin_bit_cast(s16x2, cur);
                    s16x2 b2 = __builtin_bit_cast(s16x2, v);
                    cur = __builtin_bit_cast(unsigned, __builtin_elementwise_max(a2, b2));
                }
            }
            // last segment may extend past r0+31 -> always atomic
            atomicMax(&out[(size_t)d * DIM + 2 * pair],     (cur & 0xffffu) << 16);
            atomicMax(&out[(size_t)d * DIM + 2 * pair + 1], cur & 0xffff0000u);
        }
        __syncthreads();   // (4) segmax reads done before next iter's m1 overwrite

        #pragma unroll
        for (int it = 0; it < 4; it++) pr[it] = npr[it];
    }
}

extern "C" void kernel_launch(void* const* d_in, const int* in_sizes, int n_in,
                              void* d_out, int out_size, void* d_ws, size_t ws_size,
                              hipStream_t stream) {
    const float* x  = (const float*)d_in[0];
    const int* eidx = (const int*)d_in[1];
    const float* W1 = (const float*)d_in[2];
    const float* b1 = (const float*)d_in[3];
    const float* W2 = (const float*)d_in[4];
    const float* b2 = (const float*)d_in[5];
    const float* W3 = (const float*)d_in[6];
    const float* b3 = (const float*)d_in[7];

    char* ws = (char*)d_ws;
    unsigned short* gA  = (unsigned short*)ws;                     // 12,800,000 B
    unsigned short* gB  = (unsigned short*)(ws + 12800000);        // 12,800,000 B
    unsigned short* W1t = (unsigned short*)(ws + 25600000);        // 32,768 B
    unsigned short* Wat = (unsigned short*)(ws + 25632768);        // 32,768 B
    unsigned short* Wbt = (unsigned short*)(ws + 25665536);        // 32,768 B
    unsigned short* W3t = (unsigned short*)(ws + 25698304);        // 32,768 B
    int* cnt            = (int*)(ws + 25731072);                   // 200,000 B
    int* aux            = (int*)(ws + 25931072);                   // 1,024 B
    int2* spair         = (int2*)(ws + 25932096);                  // 6,400,000 B -> 32,332,096 total

    (void)hipMemsetAsync(cnt, 0, N_NODES * sizeof(int), stream);
    prep_kernel<<<256 + HIST_B + OUTZ_B, 256, 0, stream>>>(W1, W2, W3, eidx,
        W1t, Wat, Wbt, W3t, cnt, (u32x4*)d_out);
    scan_node_kernel<<<SCAN_B + NODE_B, 256, 0, stream>>>(cnt, aux,
        x, W1t, Wat, Wbt, b1, b2, gA, gB);
    scatter_kernel<<<SCAT_B, 256, 0, stream>>>(eidx, cnt, aux, spair);
    edge_kernel<<<2048, 256, 0, stream>>>(gA, gB, spair, W3t, b3, (unsigned int*)d_out);
}

// Round 3
// 284.065 us; speedup vs baseline: 1.1413x; 1.1413x over previous
//
#include <hip/hip_runtime.h>
#include <hip/hip_bf16.h>

#define N_NODES 50000
#define N_EDGES 800000
#define DIM 128
#define NTILES (N_EDGES / 64)   // 12500 exactly
#define SCAN_B 196              // ceil(50000/256)
#define HIST_B 3125             // 800000/256
#define NODE_B 782              // ceil(50000/64)
#define OUTZ_B 512
#define SCAT_B 2048             // 8 sets x 256 blocks; set = bid&7 -> XCD heuristic

typedef __bf16 bf16x8 __attribute__((ext_vector_type(8)));
typedef float f32x4 __attribute__((ext_vector_type(4)));
typedef unsigned int u32x4 __attribute__((ext_vector_type(4)));
typedef short s16x2 __attribute__((ext_vector_type(2)));

__device__ __forceinline__ unsigned short f2bf(float f) {
    unsigned u = __float_as_uint(f);
    u += 0x7fffu + ((u >> 16) & 1u);          // round-to-nearest-even
    return (unsigned short)(u >> 16);
}
__device__ __forceinline__ float bf2f(unsigned short s) {
    return __uint_as_float(((unsigned)s) << 16);
}
__device__ __forceinline__ unsigned short f2bf_hw(float f) {
    __hip_bfloat16 h = __float2bfloat16(f);
    unsigned short s;
    __builtin_memcpy(&s, &h, 2);
    return s;
}
// packed bf16x2 add (v_pk_add_bf16 on gfx950) + relu via packed int16 max
// (bf16 bits: negative => sign bit => int16<0, positive ordering == float ordering)
__device__ __forceinline__ unsigned bf2_add_relu(unsigned a, unsigned b) {
    __hip_bfloat162 A, B;
    __builtin_memcpy(&A, &a, 4);
    __builtin_memcpy(&B, &b, 4);
    __hip_bfloat162 S = __hadd2(A, B);
    unsigned s;
    __builtin_memcpy(&s, &S, 4);
    s16x2 sv = __builtin_bit_cast(s16x2, s);
    s16x2 z = (s16x2){0, 0};
    return __builtin_bit_cast(unsigned, __builtin_elementwise_max(sv, z));
}

// ---- K1 (R12-proven): convert weights (blocks 0..255) + dst hist (256..3380) + zero out
// identity: [h_i, h_j-h_i] @ W2 = h_i @ (W2a - W2b) + h_j @ W2b
__global__ void prep_kernel(const float* __restrict__ W1, const float* __restrict__ W2,
                            const float* __restrict__ W3, const int* __restrict__ eidx,
                            unsigned short* __restrict__ W1t, unsigned short* __restrict__ Wat,
                            unsigned short* __restrict__ Wbt, unsigned short* __restrict__ W3t,
                            int* __restrict__ cnt, u32x4* __restrict__ outz) {
    int bid = blockIdx.x, tid = threadIdx.x;
    if (bid < 256) {
        int i = bid * 256 + tid;
        int j = i & (DIM * DIM - 1);
        int k = j >> 7, n = j & 127;
        int sec = i >> 14;
        if (sec == 0)      W1t[n * 128 + k] = f2bf(W1[k * 128 + n]);
        else if (sec == 1) Wat[n * 128 + k] = f2bf(W2[k * 128 + n] - W2[(k + 128) * 128 + n]);
        else if (sec == 2) Wbt[n * 128 + k] = f2bf(W2[(k + 128) * 128 + n]);
        else               W3t[n * 128 + k] = f2bf(W3[k * 128 + n]);
    } else if (bid < 256 + HIST_B) {
        int e = (bid - 256) * 256 + tid;      // exactly covers 800000
        atomicAdd(&cnt[eidx[N_EDGES + e]], 1);
    } else {
        int b = bid - 256 - HIST_B;
        u32x4 z = (u32x4){0u, 0u, 0u, 0u};
        for (int i = b * 256 + tid; i < N_NODES * DIM / 4; i += OUTZ_B * 256) outz[i] = z;
    }
}

// ---- K2 (R12-proven): scanA (blocks 0..195) + node GEMMs (blocks 196..977)
// node: h = bf16(x@W1+b1) -> LDS -> gA = bf16(h@Wa + b2), gB = bf16(h@Wb)
__global__ __launch_bounds__(256, 2) void scan_node_kernel(
        int* __restrict__ cnt, int* __restrict__ aux,
        const float* __restrict__ x, const unsigned short* __restrict__ W1t,
        const unsigned short* __restrict__ Wat, const unsigned short* __restrict__ Wbt,
        const float* __restrict__ b1, const float* __restrict__ b2,
        unsigned short* __restrict__ gA, unsigned short* __restrict__ gB) {
    __shared__ __align__(16) unsigned short w1t[128 * 136];   // head doubles as scan buf
    __shared__ __align__(16) unsigned short h_lds[64 * 136];
    int tid = threadIdx.x, bid = blockIdx.x;
    if (bid < SCAN_B) {
        int* buf = (int*)w1t;
        int i = bid * 256 + tid;
        int v = (i < N_NODES) ? cnt[i] : 0;
        buf[tid] = v;
        __syncthreads();
        for (int off = 1; off < 256; off <<= 1) {
            int u = (tid >= off) ? buf[tid - off] : 0;
            __syncthreads();
            buf[tid] += u;
            __syncthreads();
        }
        if (i < N_NODES) cnt[i] = buf[tid] - v;
        if (tid == 255) aux[bid] = buf[255];
        return;
    }
    int bl = bid - SCAN_B;
    #pragma unroll
    for (int it = 0; it < 8; it++) {
        int idx = (tid + it * 256) * 8;
        int n = idx >> 7, k = idx & 127;
        *(u32x4*)(&w1t[n * 136 + k]) = *(const u32x4*)(&W1t[idx]);
    }
    int w = tid >> 6, lane = tid & 63;
    int lr = lane & 15, q = lane >> 4;
    bf16x8 baf[2][4], bbf[2][4];
    float b2v[2];
    #pragma unroll
    for (int ct = 0; ct < 2; ct++) {
        int n = (2 * w + ct) * 16 + lr;
        #pragma unroll
        for (int kt = 0; kt < 4; kt++) {
            baf[ct][kt] = __builtin_bit_cast(bf16x8, *(const u32x4*)(&Wat[n * 128 + kt * 32 + q * 8]));
            bbf[ct][kt] = __builtin_bit_cast(bf16x8, *(const u32x4*)(&Wbt[n * 128 + kt * 32 + q * 8]));
        }
        b2v[ct] = b2[n];
    }
    __syncthreads();
    int row0 = bl * 64;
    int rowA = row0 + w * 16 + lr; if (rowA >= N_NODES) rowA = N_NODES - 1;
    {
        f32x4 acc[8];
        #pragma unroll
        for (int ct = 0; ct < 8; ct++) acc[ct] = (f32x4){0.f, 0.f, 0.f, 0.f};
        #pragma unroll
        for (int kt = 0; kt < 4; kt++) {
            const float* ap = x + (size_t)rowA * DIM + kt * 32 + q * 8;
            f32x4 x0 = *(const f32x4*)(ap);
            f32x4 x1 = *(const f32x4*)(ap + 4);
            bf16x8 a;
            #pragma unroll
            for (int j = 0; j < 4; j++) { a[j] = (__bf16)x0[j]; a[j + 4] = (__bf16)x1[j]; }
            #pragma unroll
            for (int ct = 0; ct < 8; ct++) {
                bf16x8 b = __builtin_bit_cast(bf16x8,
                    *(const u32x4*)(&w1t[(ct * 16 + lr) * 136 + kt * 32 + q * 8]));
                acc[ct] = __builtin_amdgcn_mfma_f32_16x16x32_bf16(a, b, acc[ct], 0, 0, 0);
            }
        }
        #pragma unroll
        for (int ct = 0; ct < 8; ct++) {
            int col = ct * 16 + lr;
            float bias = b1[col];
            #pragma unroll
            for (int r = 0; r < 4; r++)   // C/D: col=lane&15, row=quad*4+reg
                h_lds[(w * 16 + q * 4 + r) * 136 + col] = f2bf(acc[ct][r] + bias);
        }
    }
    __syncthreads();
    {
        f32x4 accA[4][2], accB[4][2];
        #pragma unroll
        for (int rt = 0; rt < 4; rt++)
            #pragma unroll
            for (int ct = 0; ct < 2; ct++) {
                accA[rt][ct] = (f32x4){0.f, 0.f, 0.f, 0.f};
                accB[rt][ct] = (f32x4){0.f, 0.f, 0.f, 0.f};
            }
        #pragma unroll
        for (int kt = 0; kt < 4; kt++) {
            #pragma unroll
            for (int rt = 0; rt < 4; rt++) {
                bf16x8 a = __builtin_bit_cast(bf16x8,
                    *(const u32x4*)(&h_lds[(rt * 16 + lr) * 136 + kt * 32 + q * 8]));
                accA[rt][0] = __builtin_amdgcn_mfma_f32_16x16x32_bf16(a, baf[0][kt], accA[rt][0], 0, 0, 0);
                accA[rt][1] = __builtin_amdgcn_mfma_f32_16x16x32_bf16(a, baf[1][kt], accA[rt][1], 0, 0, 0);
                accB[rt][0] = __builtin_amdgcn_mfma_f32_16x16x32_bf16(a, bbf[0][kt], accB[rt][0], 0, 0, 0);
                accB[rt][1] = __builtin_amdgcn_mfma_f32_16x16x32_bf16(a, bbf[1][kt], accB[rt][1], 0, 0, 0);
            }
        }
        #pragma unroll
        for (int rt = 0; rt < 4; rt++) {
            #pragma unroll
            for (int ct = 0; ct < 2; ct++) {
                int col = (2 * w + ct) * 16 + lr;
                #pragma unroll
                for (int r = 0; r < 4; r++) {
                    int row = row0 + rt * 16 + q * 4 + r;
                    if (row < N_NODES) {
                        gA[(size_t)row * DIM + col] = f2bf(accA[rt][ct][r] + b2v[ct]);
                        gB[(size_t)row * DIM + col] = f2bf(accB[rt][ct][r]);
                    }
                }
            }
        }
    }
}

// ---- K3 (R12-proven): XCD-binned scatter
__global__ __launch_bounds__(256) void scatter_kernel(
        const int* __restrict__ eidx, int* __restrict__ cursor, const int* __restrict__ aux,
        int2* __restrict__ spair) {
    __shared__ int buf[256];
    int tid = threadIdx.x, bid = blockIdx.x;
    int v = (tid < SCAN_B) ? aux[tid] : 0;
    buf[tid] = v;
    __syncthreads();
    for (int off = 1; off < 256; off <<= 1) {
        int u = (tid >= off) ? buf[tid - off] : 0;
        __syncthreads();
        buf[tid] += u;
        __syncthreads();
    }
    int excl = buf[tid] - v;
    __syncthreads();
    buf[tid] = excl;
    __syncthreads();
    int set = bid & 7;
    int j = bid >> 3;
    for (int e = j * 256 + tid; e < N_EDGES; e += (SCAT_B / 8) * 256) {
        int d = eidx[N_EDGES + e];
        if (((d >> 8) & 7) == set) {
            int s = eidx[e];
            int p = atomicAdd(&cursor[d], 1) + buf[d >> 8];
            spair[p] = make_int2(s, d);
        }
    }
}

// ---- K4: R12 structure (2 LDS buffers, bounds(256,4), pure-atomic segmax) +
// R14 change: T14 async-STAGE register pipeline. Tile t+1's gA/gB gathers are
// issued right after barrier (1) of tile t (spair prefetched two tiles ahead),
// held in regs across the GEMM, staged to LDS at next loop top as pure
// LDS/VALU work. Global latency hides under GEMM+m2+segmax for ALL waves
// (R12 hid it only under segmax, only for waves 2-3). Traffic/occupancy
// unchanged vs R12 — the R13 L2-thrash failure mode is structurally avoided.
__global__ __launch_bounds__(256, 4) void edge_kernel(
        const unsigned short* __restrict__ gA,
        const unsigned short* __restrict__ gB,
        const int2* __restrict__ spair,
        const unsigned short* __restrict__ W3t,
        const float* __restrict__ b3,
        unsigned int* __restrict__ out) {
    __shared__ __align__(16) unsigned short m1_lds[64 * 136];
    __shared__ __align__(16) unsigned short m2_lds[64 * 136];
    __shared__ int s_dst[2][64];

    int tid = threadIdx.x;
    int w = tid >> 6, lane = tid & 63;
    int lr = lane & 15, q = lane >> 4;
    int tr = tid >> 4;
    int c = (tid & 15) * 8;

    bf16x8 b3f[2][4];
    float b3v[2];
    #pragma unroll
    for (int ct = 0; ct < 2; ct++) {
        int n = (2 * w + ct) * 16 + lr;
        #pragma unroll
        for (int kt = 0; kt < 4; kt++)
            b3f[ct][kt] = __builtin_bit_cast(bf16x8, *(const u32x4*)(&W3t[n * 128 + kt * 32 + q * 8]));
        b3v[ct] = b3[n];
    }

    const int G = (int)gridDim.x;
    int tb = blockIdx.x;
    int sel = 0;

    int2 pcur[4], pnxt[4];
    u32x4 ga_r[4], gb_r[4];
    {
        int eb = tb * 64;
        #pragma unroll
        for (int it = 0; it < 4; it++) pcur[it] = spair[eb + tr + 16 * it];
        #pragma unroll
        for (int it = 0; it < 4; it++) {
            ga_r[it] = *(const u32x4*)(&gA[(size_t)pcur[it].y * DIM + c]);
            gb_r[it] = *(const u32x4*)(&gB[(size_t)pcur[it].x * DIM + c]);
        }
        int nx = tb + G;
        if (nx < NTILES) {
            int eb2 = nx * 64;
            #pragma unroll
            for (int it = 0; it < 4; it++) pnxt[it] = spair[eb2 + tr + 16 * it];
        }
    }

    for (; tb < NTILES; tb += G) {
        // stage tile tb from prefetched regs: pure VALU+LDS (no global latency here)
        #pragma unroll
        for (int it = 0; it < 4; it++) {
            int t = tr + 16 * it;
            u32x4 m;
            #pragma unroll
            for (int jj = 0; jj < 4; jj++)
                m[jj] = bf2_add_relu(ga_r[it][jj], gb_r[it][jj]);
            *(u32x4*)(&m1_lds[t * 136 + c]) = m;
        }
        if ((tid & 15) == 0) {
            #pragma unroll
            for (int it = 0; it < 4; it++) s_dst[sel][tr + 16 * it] = pcur[it].y;
        }
        __syncthreads();   // (1) m1 + s_dst ready; also orders segmax(t-1) before m2 writes(t)

        int nx = tb + G;
        // issue tile t+1's gathers NOW — latency hides under GEMM+m2+segmax
        if (nx < NTILES) {
            #pragma unroll
            for (int it = 0; it < 4; it++) {
                ga_r[it] = *(const u32x4*)(&gA[(size_t)pnxt[it].y * DIM + c]);
                gb_r[it] = *(const u32x4*)(&gB[(size_t)pnxt[it].x * DIM + c]);
            }
        }
        // prefetch spair two tiles ahead (addresses for next iteration's gather issue)
        int nx2 = tb + 2 * G;
        int2 pn2[4];
        if (nx2 < NTILES) {
            int eb2 = nx2 * 64;
            #pragma unroll
            for (int it = 0; it < 4; it++) pn2[it] = spair[eb2 + tr + 16 * it];
        }

        f32x4 acc2[4][2];
        #pragma unroll
        for (int rt = 0; rt < 4; rt++)
            #pragma unroll
            for (int ct = 0; ct < 2; ct++) acc2[rt][ct] = (f32x4){0.f, 0.f, 0.f, 0.f};
        #pragma unroll
        for (int kt = 0; kt < 4; kt++) {
            #pragma unroll
            for (int rt = 0; rt < 4; rt++) {
                bf16x8 a = __builtin_bit_cast(bf16x8,
                    *(const u32x4*)(&m1_lds[(rt * 16 + lr) * 136 + kt * 32 + q * 8]));
                acc2[rt][0] = __builtin_amdgcn_mfma_f32_16x16x32_bf16(a, b3f[0][kt], acc2[rt][0], 0, 0, 0);
                acc2[rt][1] = __builtin_amdgcn_mfma_f32_16x16x32_bf16(a, b3f[1][kt], acc2[rt][1], 0, 0, 0);
            }
        }
        #pragma unroll
        for (int rt = 0; rt < 4; rt++) {
            #pragma unroll
            for (int ct = 0; ct < 2; ct++) {
                int col = (2 * w + ct) * 16 + lr;
                #pragma unroll
                for (int r = 0; r < 4; r++)
                    m2_lds[(rt * 16 + q * 4 + r) * 136 + col] = f2bf_hw(fmaxf(acc2[rt][ct][r] + b3v[ct], 0.f));
            }
        }
        __syncthreads();   // (2) m2 ready

        // segmax: threads 0..127 -> (col pair = tid&63, row group = tid>>6 of 32 rows)
        if (tid < 128) {
            int pair = tid & 63;
            int g = tid >> 6;                           // == wave index (0 or 1)
            const unsigned* m2p = (const unsigned*)m2_lds;   // [64][68] dwords
            int r0 = g * 32;
            unsigned cur = m2p[r0 * 68 + pair];
            int d = s_dst[sel][r0];                     // wave-uniform
            #pragma unroll 4
            for (int i = 1; i < 32; i++) {
                int dn = s_dst[sel][r0 + i];            // wave-uniform
                unsigned v = m2p[(r0 + i) * 68 + pair];
                if (dn != d) {                          // wave-uniform branch
                    atomicMax(&out[(size_t)d * DIM + 2 * pair],     (cur & 0xffffu) << 16);
                    atomicMax(&out[(size_t)d * DIM + 2 * pair + 1], cur & 0xffff0000u);
                    d = dn; cur = v;
                } else {
                    s16x2 a2 = __builtin_bit_cast(s16x2, cur);
                    s16x2 b2 = __builtin_bit_cast(s16x2, v);
                    cur = __builtin_bit_cast(unsigned, __builtin_elementwise_max(a2, b2));
                }
            }
            atomicMax(&out[(size_t)d * DIM + 2 * pair],     (cur & 0xffffu) << 16);
            atomicMax(&out[(size_t)d * DIM + 2 * pair + 1], cur & 0xffff0000u);
        }
        // no trailing barrier: next iter's m1/s_dst[sel^1] writes don't touch m2/s_dst[sel];
        // waves 2-3 run ahead into the next staging while waves 0-1 finish segmax.

        sel ^= 1;
        #pragma unroll
        for (int it = 0; it < 4; it++) { pcur[it] = pnxt[it]; pnxt[it] = pn2[it]; }
    }
}

extern "C" void kernel_launch(void* const* d_in, const int* in_sizes, int n_in,
                              void* d_out, int out_size, void* d_ws, size_t ws_size,
                              hipStream_t stream) {
    const float* x  = (const float*)d_in[0];
    const int* eidx = (const int*)d_in[1];
    const float* W1 = (const float*)d_in[2];
    const float* b1 = (const float*)d_in[3];
    const float* W2 = (const float*)d_in[4];
    const float* b2 = (const float*)d_in[5];
    const float* W3 = (const float*)d_in[6];
    const float* b3 = (const float*)d_in[7];

    char* ws = (char*)d_ws;
    unsigned short* gA  = (unsigned short*)ws;                     // 12,800,000 B
    unsigned short* gB  = (unsigned short*)(ws + 12800000);        // 12,800,000 B
    unsigned short* W1t = (unsigned short*)(ws + 25600000);        // 32,768 B
    unsigned short* Wat = (unsigned short*)(ws + 25632768);        // 32,768 B
    unsigned short* Wbt = (unsigned short*)(ws + 25665536);        // 32,768 B
    unsigned short* W3t = (unsigned short*)(ws + 25698304);        // 32,768 B
    int* cnt            = (int*)(ws + 25731072);                   // 200,000 B
    int* aux            = (int*)(ws + 25931072);                   // 1,024 B
    int2* spair         = (int2*)(ws + 25932096);                  // 6,400,000 B -> 32,332,096 total

    (void)hipMemsetAsync(cnt, 0, N_NODES * sizeof(int), stream);
    prep_kernel<<<256 + HIST_B + OUTZ_B, 256, 0, stream>>>(W1, W2, W3, eidx,
        W1t, Wat, Wbt, W3t, cnt, (u32x4*)d_out);
    scan_node_kernel<<<SCAN_B + NODE_B, 256, 0, stream>>>(cnt, aux,
        x, W1t, Wat, Wbt, b1, b2, gA, gB);
    scatter_kernel<<<SCAT_B, 256, 0, stream>>>(eidx, cnt, aux, spair);
    edge_kernel<<<2048, 256, 0, stream>>>(gA, gB, spair, W3t, b3, (unsigned int*)d_out);
}

// Round 4
// 255.637 us; speedup vs baseline: 1.2682x; 1.1112x over previous
//
#include <hip/hip_runtime.h>
#include <hip/hip_bf16.h>

#define N_NODES 50000
#define N_EDGES 800000
#define DIM 128
#define NTILES (N_EDGES / 64)   // 12500 exactly
#define SCAN_B 196              // ceil(50000/256)
#define HIST_B 3125             // 800000/256
#define NODE_B 782              // ceil(50000/64)
#define OUTZ_B 512
#define SCAT_B 2048             // 8 sets x 256 blocks; set = bid&7 -> XCD heuristic

typedef __bf16 bf16x8 __attribute__((ext_vector_type(8)));
typedef float f32x4 __attribute__((ext_vector_type(4)));
typedef unsigned int u32x4 __attribute__((ext_vector_type(4)));
typedef short s16x2 __attribute__((ext_vector_type(2)));

__device__ __forceinline__ unsigned short f2bf(float f) {
    unsigned u = __float_as_uint(f);
    u += 0x7fffu + ((u >> 16) & 1u);          // round-to-nearest-even
    return (unsigned short)(u >> 16);
}
__device__ __forceinline__ float bf2f(unsigned short s) {
    return __uint_as_float(((unsigned)s) << 16);
}
__device__ __forceinline__ unsigned short f2bf_hw(float f) {
    __hip_bfloat16 h = __float2bfloat16(f);
    unsigned short s;
    __builtin_memcpy(&s, &h, 2);
    return s;
}
// packed bf16x2 add (v_pk_add_bf16 on gfx950) + relu via packed int16 max
// (bf16 bits: negative => sign bit => int16<0, positive ordering == float ordering)
__device__ __forceinline__ unsigned bf2_add_relu(unsigned a, unsigned b) {
    __hip_bfloat162 A, B;
    __builtin_memcpy(&A, &a, 4);
    __builtin_memcpy(&B, &b, 4);
    __hip_bfloat162 S = __hadd2(A, B);
    unsigned s;
    __builtin_memcpy(&s, &S, 4);
    s16x2 sv = __builtin_bit_cast(s16x2, s);
    s16x2 z = (s16x2){0, 0};
    return __builtin_bit_cast(unsigned, __builtin_elementwise_max(sv, z));
}

// ---- K1 (R12-proven): convert weights (blocks 0..255) + dst hist (256..3380) + zero out
// identity: [h_i, h_j-h_i] @ W2 = h_i @ (W2a - W2b) + h_j @ W2b
__global__ void prep_kernel(const float* __restrict__ W1, const float* __restrict__ W2,
                            const float* __restrict__ W3, const int* __restrict__ eidx,
                            unsigned short* __restrict__ W1t, unsigned short* __restrict__ Wat,
                            unsigned short* __restrict__ Wbt, unsigned short* __restrict__ W3t,
                            int* __restrict__ cnt, u32x4* __restrict__ outz) {
    int bid = blockIdx.x, tid = threadIdx.x;
    if (bid < 256) {
        int i = bid * 256 + tid;
        int j = i & (DIM * DIM - 1);
        int k = j >> 7, n = j & 127;
        int sec = i >> 14;
        if (sec == 0)      W1t[n * 128 + k] = f2bf(W1[k * 128 + n]);
        else if (sec == 1) Wat[n * 128 + k] = f2bf(W2[k * 128 + n] - W2[(k + 128) * 128 + n]);
        else if (sec == 2) Wbt[n * 128 + k] = f2bf(W2[(k + 128) * 128 + n]);
        else               W3t[n * 128 + k] = f2bf(W3[k * 128 + n]);
    } else if (bid < 256 + HIST_B) {
        int e = (bid - 256) * 256 + tid;      // exactly covers 800000
        atomicAdd(&cnt[eidx[N_EDGES + e]], 1);
    } else {
        int b = bid - 256 - HIST_B;
        u32x4 z = (u32x4){0u, 0u, 0u, 0u};
        for (int i = b * 256 + tid; i < N_NODES * DIM / 4; i += OUTZ_B * 256) outz[i] = z;
    }
}

// ---- K2 (R12-proven): scanA (blocks 0..195) + node GEMMs (blocks 196..977)
// node: h = bf16(x@W1+b1) -> LDS -> gA = bf16(h@Wa + b2), gB = bf16(h@Wb)
__global__ __launch_bounds__(256, 2) void scan_node_kernel(
        int* __restrict__ cnt, int* __restrict__ aux,
        const float* __restrict__ x, const unsigned short* __restrict__ W1t,
        const unsigned short* __restrict__ Wat, const unsigned short* __restrict__ Wbt,
        const float* __restrict__ b1, const float* __restrict__ b2,
        unsigned short* __restrict__ gA, unsigned short* __restrict__ gB) {
    __shared__ __align__(16) unsigned short w1t[128 * 136];   // head doubles as scan buf
    __shared__ __align__(16) unsigned short h_lds[64 * 136];
    int tid = threadIdx.x, bid = blockIdx.x;
    if (bid < SCAN_B) {
        int* buf = (int*)w1t;
        int i = bid * 256 + tid;
        int v = (i < N_NODES) ? cnt[i] : 0;
        buf[tid] = v;
        __syncthreads();
        for (int off = 1; off < 256; off <<= 1) {
            int u = (tid >= off) ? buf[tid - off] : 0;
            __syncthreads();
            buf[tid] += u;
            __syncthreads();
        }
        if (i < N_NODES) cnt[i] = buf[tid] - v;
        if (tid == 255) aux[bid] = buf[255];
        return;
    }
    int bl = bid - SCAN_B;
    #pragma unroll
    for (int it = 0; it < 8; it++) {
        int idx = (tid + it * 256) * 8;
        int n = idx >> 7, k = idx & 127;
        *(u32x4*)(&w1t[n * 136 + k]) = *(const u32x4*)(&W1t[idx]);
    }
    int w = tid >> 6, lane = tid & 63;
    int lr = lane & 15, q = lane >> 4;
    bf16x8 baf[2][4], bbf[2][4];
    float b2v[2];
    #pragma unroll
    for (int ct = 0; ct < 2; ct++) {
        int n = (2 * w + ct) * 16 + lr;
        #pragma unroll
        for (int kt = 0; kt < 4; kt++) {
            baf[ct][kt] = __builtin_bit_cast(bf16x8, *(const u32x4*)(&Wat[n * 128 + kt * 32 + q * 8]));
            bbf[ct][kt] = __builtin_bit_cast(bf16x8, *(const u32x4*)(&Wbt[n * 128 + kt * 32 + q * 8]));
        }
        b2v[ct] = b2[n];
    }
    __syncthreads();
    int row0 = bl * 64;
    int rowA = row0 + w * 16 + lr; if (rowA >= N_NODES) rowA = N_NODES - 1;
    {
        f32x4 acc[8];
        #pragma unroll
        for (int ct = 0; ct < 8; ct++) acc[ct] = (f32x4){0.f, 0.f, 0.f, 0.f};
        #pragma unroll
        for (int kt = 0; kt < 4; kt++) {
            const float* ap = x + (size_t)rowA * DIM + kt * 32 + q * 8;
            f32x4 x0 = *(const f32x4*)(ap);
            f32x4 x1 = *(const f32x4*)(ap + 4);
            bf16x8 a;
            #pragma unroll
            for (int j = 0; j < 4; j++) { a[j] = (__bf16)x0[j]; a[j + 4] = (__bf16)x1[j]; }
            #pragma unroll
            for (int ct = 0; ct < 8; ct++) {
                bf16x8 b = __builtin_bit_cast(bf16x8,
                    *(const u32x4*)(&w1t[(ct * 16 + lr) * 136 + kt * 32 + q * 8]));
                acc[ct] = __builtin_amdgcn_mfma_f32_16x16x32_bf16(a, b, acc[ct], 0, 0, 0);
            }
        }
        #pragma unroll
        for (int ct = 0; ct < 8; ct++) {
            int col = ct * 16 + lr;
            float bias = b1[col];
            #pragma unroll
            for (int r = 0; r < 4; r++)   // C/D: col=lane&15, row=quad*4+reg
                h_lds[(w * 16 + q * 4 + r) * 136 + col] = f2bf(acc[ct][r] + bias);
        }
    }
    __syncthreads();
    {
        f32x4 accA[4][2], accB[4][2];
        #pragma unroll
        for (int rt = 0; rt < 4; rt++)
            #pragma unroll
            for (int ct = 0; ct < 2; ct++) {
                accA[rt][ct] = (f32x4){0.f, 0.f, 0.f, 0.f};
                accB[rt][ct] = (f32x4){0.f, 0.f, 0.f, 0.f};
            }
        #pragma unroll
        for (int kt = 0; kt < 4; kt++) {
            #pragma unroll
            for (int rt = 0; rt < 4; rt++) {
                bf16x8 a = __builtin_bit_cast(bf16x8,
                    *(const u32x4*)(&h_lds[(rt * 16 + lr) * 136 + kt * 32 + q * 8]));
                accA[rt][0] = __builtin_amdgcn_mfma_f32_16x16x32_bf16(a, baf[0][kt], accA[rt][0], 0, 0, 0);
                accA[rt][1] = __builtin_amdgcn_mfma_f32_16x16x32_bf16(a, baf[1][kt], accA[rt][1], 0, 0, 0);
                accB[rt][0] = __builtin_amdgcn_mfma_f32_16x16x32_bf16(a, bbf[0][kt], accB[rt][0], 0, 0, 0);
                accB[rt][1] = __builtin_amdgcn_mfma_f32_16x16x32_bf16(a, bbf[1][kt], accB[rt][1], 0, 0, 0);
            }
        }
        #pragma unroll
        for (int rt = 0; rt < 4; rt++) {
            #pragma unroll
            for (int ct = 0; ct < 2; ct++) {
                int col = (2 * w + ct) * 16 + lr;
                #pragma unroll
                for (int r = 0; r < 4; r++) {
                    int row = row0 + rt * 16 + q * 4 + r;
                    if (row < N_NODES) {
                        gA[(size_t)row * DIM + col] = f2bf(accA[rt][ct][r] + b2v[ct]);
                        gB[(size_t)row * DIM + col] = f2bf(accB[rt][ct][r]);
                    }
                }
            }
        }
    }
}

// ---- K3 (R12-proven): XCD-binned scatter
__global__ __launch_bounds__(256) void scatter_kernel(
        const int* __restrict__ eidx, int* __restrict__ cursor, const int* __restrict__ aux,
        int2* __restrict__ spair) {
    __shared__ int buf[256];
    int tid = threadIdx.x, bid = blockIdx.x;
    int v = (tid < SCAN_B) ? aux[tid] : 0;
    buf[tid] = v;
    __syncthreads();
    for (int off = 1; off < 256; off <<= 1) {
        int u = (tid >= off) ? buf[tid - off] : 0;
        __syncthreads();
        buf[tid] += u;
        __syncthreads();
    }
    int excl = buf[tid] - v;
    __syncthreads();
    buf[tid] = excl;
    __syncthreads();
    int set = bid & 7;
    int j = bid >> 3;
    for (int e = j * 256 + tid; e < N_EDGES; e += (SCAT_B / 8) * 256) {
        int d = eidx[N_EDGES + e];
        if (((d >> 8) & 7) == set) {
            int s = eidx[e];
            int p = atomicAdd(&cursor[d], 1) + buf[d >> 8];
            spair[p] = make_int2(s, d);
        }
    }
}

// ---- K4: R12 structure (2 LDS buffers, pure-atomic segmax, no trailing barrier) +
// R15 change: gB-ONLY register prefetch (16 VGPRs). R14's spill failure mode
// (FETCH/WRITE +130MB scratch) came from 56 extra live regs at cap 128;
// here: gb_r(16) + pnx(8) under __launch_bounds__(256,3) -> cap 168, no spill.
// gA[dst] is dst-sorted (near-sequential stream) -> cheap, stays at loop top.
// gB[src] is random -> issued right after barrier(1), latency hides under
// GEMM+m2+segmax (~>1500cyc) for ALL waves.
__global__ __launch_bounds__(256, 3) void edge_kernel(
        const unsigned short* __restrict__ gA,
        const unsigned short* __restrict__ gB,
        const int2* __restrict__ spair,
        const unsigned short* __restrict__ W3t,
        const float* __restrict__ b3,
        unsigned int* __restrict__ out) {
    __shared__ __align__(16) unsigned short m1_lds[64 * 136];
    __shared__ __align__(16) unsigned short m2_lds[64 * 136];
    __shared__ int s_dst[2][64];

    int tid = threadIdx.x;
    int w = tid >> 6, lane = tid & 63;
    int lr = lane & 15, q = lane >> 4;
    int tr = tid >> 4;
    int c = (tid & 15) * 8;

    bf16x8 b3f[2][4];
    float b3v[2];
    #pragma unroll
    for (int ct = 0; ct < 2; ct++) {
        int n = (2 * w + ct) * 16 + lr;
        #pragma unroll
        for (int kt = 0; kt < 4; kt++)
            b3f[ct][kt] = __builtin_bit_cast(bf16x8, *(const u32x4*)(&W3t[n * 128 + kt * 32 + q * 8]));
        b3v[ct] = b3[n];
    }

    const int G = (int)gridDim.x;
    int tb = blockIdx.x;
    int sel = 0;

    int2 pcur[4];
    u32x4 gb_r[4];
    {
        int eb = tb * 64;
        #pragma unroll
        for (int it = 0; it < 4; it++) pcur[it] = spair[eb + tr + 16 * it];
        #pragma unroll
        for (int it = 0; it < 4; it++)
            gb_r[it] = *(const u32x4*)(&gB[(size_t)pcur[it].x * DIM + c]);
    }

    for (; tb < NTILES; tb += G) {
        // m1 = relu(gA[dst] + gB_prefetched): ga is a near-sequential stream (cheap)
        #pragma unroll
        for (int it = 0; it < 4; it++) {
            int t = tr + 16 * it;
            u32x4 ga = *(const u32x4*)(&gA[(size_t)pcur[it].y * DIM + c]);
            u32x4 m;
            #pragma unroll
            for (int jj = 0; jj < 4; jj++)
                m[jj] = bf2_add_relu(ga[jj], gb_r[it][jj]);
            *(u32x4*)(&m1_lds[t * 136 + c]) = m;
        }
        if ((tid & 15) == 0) {
            #pragma unroll
            for (int it = 0; it < 4; it++) s_dst[sel][tr + 16 * it] = pcur[it].y;
        }
        __syncthreads();   // (1) m1 + s_dst ready; also orders segmax(t-1) before m2 writes(t)

        // prefetch next tile: spair then dependent random gB gathers — both hide
        // under the GEMM + m2 + segmax below
        int nx = tb + G;
        int2 pnx[4];
        if (nx < NTILES) {
            int eb = nx * 64;
            #pragma unroll
            for (int it = 0; it < 4; it++) pnx[it] = spair[eb + tr + 16 * it];
            #pragma unroll
            for (int it = 0; it < 4; it++)
                gb_r[it] = *(const u32x4*)(&gB[(size_t)pnx[it].x * DIM + c]);
        }

        f32x4 acc2[4][2];
        #pragma unroll
        for (int rt = 0; rt < 4; rt++)
            #pragma unroll
            for (int ct = 0; ct < 2; ct++) acc2[rt][ct] = (f32x4){0.f, 0.f, 0.f, 0.f};
        #pragma unroll
        for (int kt = 0; kt < 4; kt++) {
            #pragma unroll
            for (int rt = 0; rt < 4; rt++) {
                bf16x8 a = __builtin_bit_cast(bf16x8,
                    *(const u32x4*)(&m1_lds[(rt * 16 + lr) * 136 + kt * 32 + q * 8]));
                acc2[rt][0] = __builtin_amdgcn_mfma_f32_16x16x32_bf16(a, b3f[0][kt], acc2[rt][0], 0, 0, 0);
                acc2[rt][1] = __builtin_amdgcn_mfma_f32_16x16x32_bf16(a, b3f[1][kt], acc2[rt][1], 0, 0, 0);
            }
        }
        #pragma unroll
        for (int rt = 0; rt < 4; rt++) {
            #pragma unroll
            for (int ct = 0; ct < 2; ct++) {
                int col = (2 * w + ct) * 16 + lr;
                #pragma unroll
                for (int r = 0; r < 4; r++)
                    m2_lds[(rt * 16 + q * 4 + r) * 136 + col] = f2bf_hw(fmaxf(acc2[rt][ct][r] + b3v[ct], 0.f));
            }
        }
        __syncthreads();   // (2) m2 ready

        // segmax: threads 0..127 -> (col pair = tid&63, row group = tid>>6 of 32 rows)
        if (tid < 128) {
            int pair = tid & 63;
            int g = tid >> 6;                           // == wave index (0 or 1)
            const unsigned* m2p = (const unsigned*)m2_lds;   // [64][68] dwords
            int r0 = g * 32;
            unsigned cur = m2p[r0 * 68 + pair];
            int d = s_dst[sel][r0];                     // wave-uniform
            #pragma unroll 4
            for (int i = 1; i < 32; i++) {
                int dn = s_dst[sel][r0 + i];            // wave-uniform
                unsigned v = m2p[(r0 + i) * 68 + pair];
                if (dn != d) {                          // wave-uniform branch
                    atomicMax(&out[(size_t)d * DIM + 2 * pair],     (cur & 0xffffu) << 16);
                    atomicMax(&out[(size_t)d * DIM + 2 * pair + 1], cur & 0xffff0000u);
                    d = dn; cur = v;
                } else {
                    s16x2 a2 = __builtin_bit_cast(s16x2, cur);
                    s16x2 b2 = __builtin_bit_cast(s16x2, v);
                    cur = __builtin_bit_cast(unsigned, __builtin_elementwise_max(a2, b2));
                }
            }
            atomicMax(&out[(size_t)d * DIM + 2 * pair],     (cur & 0xffffu) << 16);
            atomicMax(&out[(size_t)d * DIM + 2 * pair + 1], cur & 0xffff0000u);
        }
        // no trailing barrier: next iter's m1/s_dst[sel^1] writes don't touch m2/s_dst[sel];
        // waves 2-3 run ahead into the next staging while waves 0-1 finish segmax.

        sel ^= 1;
        #pragma unroll
        for (int it = 0; it < 4; it++) pcur[it] = pnx[it];
    }
}

extern "C" void kernel_launch(void* const* d_in, const int* in_sizes, int n_in,
                              void* d_out, int out_size, void* d_ws, size_t ws_size,
                              hipStream_t stream) {
    const float* x  = (const float*)d_in[0];
    const int* eidx = (const int*)d_in[1];
    const float* W1 = (const float*)d_in[2];
    const float* b1 = (const float*)d_in[3];
    const float* W2 = (const float*)d_in[4];
    const float* b2 = (const float*)d_in[5];
    const float* W3 = (const float*)d_in[6];
    const float* b3 = (const float*)d_in[7];

    char* ws = (char*)d_ws;
    unsigned short* gA  = (unsigned short*)ws;                     // 12,800,000 B
    unsigned short* gB  = (unsigned short*)(ws + 12800000);        // 12,800,000 B
    unsigned short* W1t = (unsigned short*)(ws + 25600000);        // 32,768 B
    unsigned short* Wat = (unsigned short*)(ws + 25632768);        // 32,768 B
    unsigned short* Wbt = (unsigned short*)(ws + 25665536);        // 32,768 B
    unsigned short* W3t = (unsigned short*)(ws + 25698304);        // 32,768 B
    int* cnt            = (int*)(ws + 25731072);                   // 200,000 B
    int* aux            = (int*)(ws + 25931072);                   // 1,024 B
    int2* spair         = (int2*)(ws + 25932096);                  // 6,400,000 B -> 32,332,096 total

    (void)hipMemsetAsync(cnt, 0, N_NODES * sizeof(int), stream);
    prep_kernel<<<256 + HIST_B + OUTZ_B, 256, 0, stream>>>(W1, W2, W3, eidx,
        W1t, Wat, Wbt, W3t, cnt, (u32x4*)d_out);
    scan_node_kernel<<<SCAN_B + NODE_B, 256, 0, stream>>>(cnt, aux,
        x, W1t, Wat, Wbt, b1, b2, gA, gB);
    scatter_kernel<<<SCAT_B, 256, 0, stream>>>(eidx, cnt, aux, spair);
    edge_kernel<<<2048, 256, 0, stream>>>(gA, gB, spair, W3t, b3, (unsigned int*)d_out);
}